// Round 7
// baseline (391.358 us; speedup 1.0000x reference)
//
#include <hip/hip_runtime.h>
#include <hip/hip_bf16.h>
#include <stdint.h>

#define N_NODES 50000
#define MPAD    50048          // 782 * 64
#define IN_DIM  256
#define EDGES   800000
#define EPRIME  (EDGES + N_NODES)
#define NGRAPH  64
#define GN_EPS  1e-5f
#define ECPAD   53248          // 208 * 256 = 13 * 4096, >= N_NODES
#define HIST_BLOCKS 3321       // ceil(EPRIME/256)
#define PREP_BLOCKS 512
#define MSG_SPLIT 4
#define MSG_RANGE (N_NODES / MSG_SPLIT)   // 12500

typedef __attribute__((ext_vector_type(8))) short short8;
typedef __attribute__((ext_vector_type(4))) float floatx4;
typedef __attribute__((ext_vector_type(2))) float float2v;

__device__ __forceinline__ uint32_t pk2bf(float a, float b) {
    union { __hip_bfloat162 h; uint32_t u; } cv;
    cv.h = __float22bfloat162_rn(make_float2(a, b));
    return cv.u;
}

__device__ __forceinline__ unsigned short f2b(float f) {
    uint32_t u = __float_as_uint(f);
    u += 0x7fffu + ((u >> 16) & 1u);   // RTNE
    return (unsigned short)(u >> 16);
}

__device__ __forceinline__ float2v up2(uint32_t u) {
    float2v r;
    r[0] = __uint_as_float(u << 16);
    r[1] = __uint_as_float(u & 0xffff0000u);
    return r;
}

// ---------- fused: Wt build (blocks < 512) + histograms (blocks >= 512) ----------
__global__ __launch_bounds__(256) void k_pre(const float* __restrict__ Wl,
                                             const float* __restrict__ Wr,
                                             unsigned short* __restrict__ Wt,
                                             const int* __restrict__ ei,
                                             const int* __restrict__ batch,
                                             int* __restrict__ ecount,
                                             int* __restrict__ ncount,
                                             int* __restrict__ sedge) {
    if (blockIdx.x < PREP_BLOCKS) {
        int idx = blockIdx.x * 256 + threadIdx.x;     // 512*256
        int n = idx >> 8, k = idx & 255;
        float v = (n < 256) ? Wl[k * 256 + n] : Wr[k * 256 + (n - 256)];
        Wt[idx] = f2b(v);
        return;
    }
    __shared__ int hist[NGRAPH];
    if (threadIdx.x < NGRAPH) hist[threadIdx.x] = 0;
    __syncthreads();
    int e = (blockIdx.x - PREP_BLOCKS) * 256 + threadIdx.x;
    if (e < EPRIME) {
        int d = (e < EDGES) ? ei[EDGES + e] : (e - EDGES);
        atomicAdd(&ecount[d], 1);
    }
    if (e < N_NODES) atomicAdd(&hist[batch[e]], 1);
    if (blockIdx.x == PREP_BLOCKS && threadIdx.x < 192) sedge[EPRIME + threadIdx.x] = 0;
    __syncthreads();
    if (threadIdx.x < NGRAPH && hist[threadIdx.x])
        atomicAdd(&ncount[threadIdx.x], hist[threadIdx.x]);
}

// ---------- GEMM: [XL|XR] = bf16(x) @ [W_l|W_r] ----------
__global__ __launch_bounds__(512) void k_gemm(const float* __restrict__ x,
                                              const unsigned short* __restrict__ Wt,
                                              const float* __restrict__ bl,
                                              const float* __restrict__ br,
                                              unsigned short* __restrict__ XL,
                                              unsigned short* __restrict__ XR) {
    __shared__ unsigned short As[64 * 256];       // 32 KB
    int rbase = blockIdx.x * 64;
    int tid = threadIdx.x;

#pragma unroll
    for (int it = 0; it < 4; ++it) {
        int c = it * 512 + tid;
        int row = c >> 5, ch = c & 31;
        int gr = rbase + row;
        float4 f0, f1;
        if (gr < N_NODES) {
            const float4* src = (const float4*)(x + (size_t)gr * 256 + ch * 8);
            f0 = src[0]; f1 = src[1];
        } else {
            f0 = make_float4(0.f,0.f,0.f,0.f); f1 = f0;
        }
        uint32_t p0 = pk2bf(f0.x, f0.y), p1 = pk2bf(f0.z, f0.w);
        uint32_t p2 = pk2bf(f1.x, f1.y), p3 = pk2bf(f1.z, f1.w);
        uint4 hv = make_uint4(p0, p1, p2, p3);
        *(uint4*)(As + row * 256 + (ch ^ (row & 7)) * 8) = hv;
    }
    __syncthreads();

    int w = tid >> 6;
    int l = tid & 63;
    int m = l & 15, q = l >> 4;

    floatx4 acc[4][4];
#pragma unroll
    for (int rf = 0; rf < 4; ++rf)
#pragma unroll
        for (int cf = 0; cf < 4; ++cf)
            acc[rf][cf] = (floatx4){0.f, 0.f, 0.f, 0.f};

    const unsigned short* wbase = Wt + (size_t)(w * 64) * 256;

#pragma unroll
    for (int kk = 0; kk < 8; ++kk) {
        short8 a[4];
#pragma unroll
        for (int rf = 0; rf < 4; ++rf) {
            int row = rf * 16 + m;
            int ch = (kk * 4 + q) ^ (row & 7);
            a[rf] = *(const short8*)(As + row * 256 + ch * 8);
        }
#pragma unroll
        for (int cf = 0; cf < 4; ++cf) {
            short8 b = *(const short8*)(wbase + (size_t)(cf * 16 + m) * 256 + kk * 32 + q * 8);
#pragma unroll
            for (int rf = 0; rf < 4; ++rf)   // A-slot = W frag -> D = C^T tile
                acc[rf][cf] = __builtin_amdgcn_mfma_f32_16x16x32_bf16(b, a[rf], acc[rf][cf], 0, 0, 0);
        }
    }

    // D layout (transposed compute): node = lane&15, channel = q*4 + reg.
    unsigned short* obase = (w < 4) ? XL : XR;
    const float* bptr = (w < 4) ? bl : br;
    int cb = (w & 3) * 64;
#pragma unroll
    for (int cf = 0; cf < 4; ++cf) {
        int chb = cb + cf * 16 + q * 4;
        float4 bv = *(const float4*)(bptr + chb);
#pragma unroll
        for (int rf = 0; rf < 4; ++rf) {
            int node = rbase + rf * 16 + m;
            uint2 o;
            o.x = pk2bf(acc[rf][cf][0] + bv.x, acc[rf][cf][1] + bv.y);
            o.y = pk2bf(acc[rf][cf][2] + bv.z, acc[rf][cf][3] + bv.w);
            *(uint2*)(obase + (size_t)node * 256 + chb) = o;  // pad rows exist
        }
    }
}

// ---------- single-workgroup device-wide exclusive scan of ecount ----------
__global__ __launch_bounds__(1024) void k_scan_all(const int* __restrict__ ecount,
                                                   int* __restrict__ estart,
                                                   int* __restrict__ ecursor) {
    __shared__ int wsum[16];
    int t = threadIdx.x, w = t >> 6, l = t & 63;
    int carry = 0;
    for (int base = 0; base < ECPAD; base += 4096) {
        int4 v = ((const int4*)(ecount + base))[t];
        int s = v.x + v.y + v.z + v.w;
        int sc = s;
#pragma unroll
        for (int off = 1; off < 64; off <<= 1) {
            int n = __shfl_up(sc, off);
            sc += (l >= off) ? n : 0;
        }
        if (l == 63) wsum[w] = sc;
        __syncthreads();
        int woff = 0, ctot = 0;
#pragma unroll
        for (int i = 0; i < 16; ++i) {
            int wi = wsum[i];
            woff += (i < w) ? wi : 0;
            ctot += wi;
        }
        int e0 = carry + woff + (sc - s);
        int4 o;
        o.x = e0; o.y = e0 + v.x; o.z = o.y + v.y; o.w = o.z + v.z;
        ((int4*)(estart  + base))[t] = o;
        ((int4*)(ecursor + base))[t] = o;
        carry += ctot;
        __syncthreads();   // protect wsum before next chunk overwrites
    }
}

// ---------- scatter edges into dst-sorted order (store src only) ----------
__global__ __launch_bounds__(256) void k_scatter(const int* __restrict__ ei,
                                                 int* __restrict__ ecursor,
                                                 int* __restrict__ sedge) {
    int e = blockIdx.x * 256 + threadIdx.x;
    if (e >= EPRIME) return;
    int s, d;
    if (e < EDGES) { s = ei[e]; d = ei[EDGES + e]; }
    else           { s = d = e - EDGES; }
    int pos = atomicAdd(&ecursor[d], 1);
    sedge[pos] = s;
}

// ---------- core v7: r4 body exactly (4-deep prefetch), dst-range split ----------
__global__ __launch_bounds__(256) void k_msg(const unsigned short* __restrict__ XL,
                                             const unsigned short* __restrict__ XRb,
                                             const float* __restrict__ x,
                                             const float* __restrict__ att,
                                             const float* __restrict__ bias,
                                             const int* __restrict__ sedge,
                                             const int* __restrict__ estart,
                                             const int* __restrict__ ecount,
                                             float* __restrict__ out,
                                             int lo) {
    int d = lo + (int)((blockIdx.x * 256 + threadIdx.x) >> 6);
    int l = threadIdx.x & 63;
    int lofs = l * 8;                 // byte offset of this lane's uint2 in a row

    float4 xin  = ((const float4*)(x + (size_t)d * 256))[l];
    float4 bvv  = ((const float4*)bias)[l];
    float4 attv = ((const float4*)att)[l];
    // leaky_relu(z,0.2) = 0.6z + 0.4|z|; fold coefficients into att
    float2v a601 = {0.6f * attv.x, 0.6f * attv.y};
    float2v a623 = {0.6f * attv.z, 0.6f * attv.w};
    float a40 = 0.4f * attv.x, a41 = 0.4f * attv.y;
    float a42 = 0.4f * attv.z, a43 = 0.4f * attv.w;

    uint2 xru = ((const uint2*)(XRb + (size_t)d * 256))[l];
    float2v xr01 = up2(xru.x), xr23 = up2(xru.y);

    int s0  = __builtin_amdgcn_readfirstlane(estart[d]);
    int cnt = __builtin_amdgcn_readfirstlane(ecount[d]);

    auto ldrow = [&](int src) -> uint2 {
        size_t off = ((size_t)(uint32_t)__builtin_amdgcn_readfirstlane(src)) << 9;
        return *(const uint2*)((const char*)XL + off + lofs);
    };

    float den0 = 0.f, den1 = 0.f, den2 = 0.f, den3 = 0.f;
    float2v A01 = {0.f,0.f}, A23 = {0.f,0.f};
    float2v B01 = {0.f,0.f}, B23 = {0.f,0.f};
    float2v C01 = {0.f,0.f}, C23 = {0.f,0.f};
    float2v D01 = {0.f,0.f}, D23 = {0.f,0.f};

    auto proc = [&](uint2 U, float& den, float2v& R01, float2v& R23) {
        float2v x01 = up2(U.x), x23 = up2(U.y);
        float2v z01 = x01 + xr01, z23 = x23 + xr23;
        float2v q = z01 * a601 + z23 * a623;      // 0.6 * att.z  (pk fma)
        float t0 = fmaf(fabsf(z01[0]), a40, q[0]);
        float t1 = fmaf(fabsf(z01[1]), a41, q[1]);
        t0 = fmaf(fabsf(z23[0]), a42, t0);
        t1 = fmaf(fabsf(z23[1]), a43, t1);
        float pp = t0 + t1;
        // 8-lane head reduce: xor1 (quad_perm), xor2 (quad_perm), xor4 (row_half_mirror)
        int pi = __float_as_int(pp);
        pp += __int_as_float(__builtin_amdgcn_update_dpp(0, pi, 0xB1, 0xF, 0xF, true));
        pi = __float_as_int(pp);
        pp += __int_as_float(__builtin_amdgcn_update_dpp(0, pi, 0x4E, 0xF, 0xF, true));
        pi = __float_as_int(pp);
        pp += __int_as_float(__builtin_amdgcn_update_dpp(0, pi, 0x141, 0xF, 0xF, true));
        float al = __expf(fminf(pp, 80.f));
        den += al;
        float2v al2 = {al, al};
        R01 += al2 * x01;
        R23 += al2 * x23;
    };

    // 4-deep prefetch: overshoot reads next dst's (valid) edges or zero pad
    uint2 P0 = ldrow(sedge[s0]);
    uint2 P1 = ldrow(sedge[s0 + 1]);
    uint2 P2 = ldrow(sedge[s0 + 2]);
    uint2 P3 = ldrow(sedge[s0 + 3]);

    int nq = cnt >> 2;
    for (int qq = 0; qq < nq; ++qq) {
        uint2 Q0 = P0, Q1 = P1, Q2 = P2, Q3 = P3;
        int nb = s0 + (qq + 1) * 4;
        P0 = ldrow(sedge[nb]);
        P1 = ldrow(sedge[nb + 1]);
        P2 = ldrow(sedge[nb + 2]);
        P3 = ldrow(sedge[nb + 3]);
        proc(Q0, den0, A01, A23);
        proc(Q1, den1, B01, B23);
        proc(Q2, den2, C01, C23);
        proc(Q3, den3, D01, D23);
    }
    int rem = cnt & 3;
    if (rem > 0) proc(P0, den0, A01, A23);
    if (rem > 1) proc(P1, den1, B01, B23);
    if (rem > 2) proc(P2, den2, C01, C23);

    float inv = 1.f / ((den0 + den1) + (den2 + den3) + 1e-16f);
    A01 = (A01 + B01) + (C01 + D01);
    A23 = (A23 + B23) + (C23 + D23);

    float h0 = A01[0] * inv + bvv.x + xin.x; h0 = (h0 > 0.f) ? h0 : (__expf(h0) - 1.f);
    float h1 = A01[1] * inv + bvv.y + xin.y; h1 = (h1 > 0.f) ? h1 : (__expf(h1) - 1.f);
    float h2 = A23[0] * inv + bvv.z + xin.z; h2 = (h2 > 0.f) ? h2 : (__expf(h2) - 1.f);
    float h3 = A23[1] * inv + bvv.w + xin.w; h3 = (h3 > 0.f) ? h3 : (__expf(h3) - 1.f);
    ((float4*)(out + (size_t)d * 256))[l] = make_float4(h0, h1, h2, h3);
}

// ---------- GraphNorm stats v3: float4 loads, 16 in flight, LDS reduce ----------
#define GN_ROWS 64
__global__ __launch_bounds__(256) void k_gn_sum(const float* __restrict__ h,
                                                const int* __restrict__ batch,
                                                float* __restrict__ gsum,
                                                float* __restrict__ gsq) {
    __shared__ int bsh[GN_ROWS];
    __shared__ float4 redS[4][64];
    __shared__ float4 redQ[4][64];
    int r0 = blockIdx.x * GN_ROWS;
    int t = threadIdx.x;
    if (t < GN_ROWS) {
        int i = r0 + t;
        bsh[t] = (i < N_NODES) ? batch[i] : -2;
    }
    __syncthreads();
    int l = t & 63, w = t >> 6;
    bool uni = (r0 + GN_ROWS <= N_NODES) && (bsh[0] == bsh[GN_ROWS - 1]);

    if (uni) {
        // fast path: whole block one graph; thread reads rows w, w+4, ..., w+60
        const float* hp = h + (size_t)(r0 + w) * 256 + l * 4;
        float4 s1 = make_float4(0.f, 0.f, 0.f, 0.f);
        float4 s2 = make_float4(0.f, 0.f, 0.f, 0.f);
#pragma unroll
        for (int k = 0; k < 16; ++k) {
            float4 v = *(const float4*)(hp + (size_t)k * 1024);
            s1.x += v.x; s1.y += v.y; s1.z += v.z; s1.w += v.w;
            s2.x = fmaf(v.x, v.x, s2.x);
            s2.y = fmaf(v.y, v.y, s2.y);
            s2.z = fmaf(v.z, v.z, s2.z);
            s2.w = fmaf(v.w, v.w, s2.w);
        }
        redS[w][l] = s1; redQ[w][l] = s2;
        __syncthreads();
        if (w == 0) {
            float4 b1 = redS[1][l], c1 = redS[2][l], d1 = redS[3][l];
            float4 b2 = redQ[1][l], c2 = redQ[2][l], d2 = redQ[3][l];
            s1.x += b1.x + c1.x + d1.x; s1.y += b1.y + c1.y + d1.y;
            s1.z += b1.z + c1.z + d1.z; s1.w += b1.w + c1.w + d1.w;
            s2.x += b2.x + c2.x + d2.x; s2.y += b2.y + c2.y + d2.y;
            s2.z += b2.z + c2.z + d2.z; s2.w += b2.w + c2.w + d2.w;
            int g = bsh[0];
            float* gp = gsum + g * 256 + l * 4;
            atomicAdd(gp + 0, s1.x); atomicAdd(gp + 1, s1.y);
            atomicAdd(gp + 2, s1.z); atomicAdd(gp + 3, s1.w);
            float* gq = gsq + g * 256 + l * 4;
            atomicAdd(gq + 0, s2.x); atomicAdd(gq + 1, s2.y);
            atomicAdd(gq + 2, s2.z); atomicAdd(gq + 3, s2.w);
        }
        return;
    }

    // slow path: boundary / tail block — per-row with flush-on-graph-change
    float4 s1 = make_float4(0.f, 0.f, 0.f, 0.f);
    float4 s2 = make_float4(0.f, 0.f, 0.f, 0.f);
    int g = (r0 + w < N_NODES) ? bsh[w] : -1;
    for (int j = w; j < GN_ROWS; j += 4) {
        int ii = r0 + j;
        if (ii >= N_NODES) break;
        int bg = bsh[j];
        if (bg != g) {
            float* gp = gsum + g * 256 + l * 4;
            atomicAdd(gp + 0, s1.x); atomicAdd(gp + 1, s1.y);
            atomicAdd(gp + 2, s1.z); atomicAdd(gp + 3, s1.w);
            float* gq = gsq + g * 256 + l * 4;
            atomicAdd(gq + 0, s2.x); atomicAdd(gq + 1, s2.y);
            atomicAdd(gq + 2, s2.z); atomicAdd(gq + 3, s2.w);
            s1 = make_float4(0.f, 0.f, 0.f, 0.f);
            s2 = make_float4(0.f, 0.f, 0.f, 0.f);
            g = bg;
        }
        float4 v = *(const float4*)(h + (size_t)ii * 256 + l * 4);
        s1.x += v.x; s1.y += v.y; s1.z += v.z; s1.w += v.w;
        s2.x = fmaf(v.x, v.x, s2.x);
        s2.y = fmaf(v.y, v.y, s2.y);
        s2.z = fmaf(v.z, v.z, s2.z);
        s2.w = fmaf(v.w, v.w, s2.w);
    }
    if (g >= 0) {
        float* gp = gsum + g * 256 + l * 4;
        atomicAdd(gp + 0, s1.x); atomicAdd(gp + 1, s1.y);
        atomicAdd(gp + 2, s1.z); atomicAdd(gp + 3, s1.w);
        float* gq = gsq + g * 256 + l * 4;
        atomicAdd(gq + 0, s2.x); atomicAdd(gq + 1, s2.y);
        atomicAdd(gq + 2, s2.z); atomicAdd(gq + 3, s2.w);
    }
}

// ---------- GraphNorm finalize: grid-stride, hoisted channel params ----------
#define FIN_BLOCKS 2048
__global__ __launch_bounds__(256) void k_final(float* __restrict__ out,
                                               const int* __restrict__ batch,
                                               const float* __restrict__ gsum,
                                               const float* __restrict__ gsq,
                                               const int* __restrict__ ncount,
                                               const float* __restrict__ gnw,
                                               const float* __restrict__ gnb,
                                               const float* __restrict__ gms) {
    int l = threadIdx.x & 63, wr = threadIdx.x >> 6;
    float4 wv = ((const float4*)gnw)[l];
    float4 bv = ((const float4*)gnb)[l];
    float4 sv = ((const float4*)gms)[l];
    for (int i = blockIdx.x * 4 + wr; i < N_NODES; i += FIN_BLOCKS * 4) {
        int g = batch[i];
        float inv = 1.f / fmaxf((float)ncount[g], 1.f);
        float4 hv = ((const float4*)(out + (size_t)i * 256))[l];
        float4 ms = ((const float4*)(gsum + g * 256))[l];
        float4 qs = ((const float4*)(gsq  + g * 256))[l];
        float4 o;
        {
            float m = ms.x * inv, q = qs.x * inv;
            o.x = wv.x * (hv.x - sv.x * m) * rsqrtf(q - m * m * sv.x * (2.f - sv.x) + GN_EPS) + bv.x;
        }
        {
            float m = ms.y * inv, q = qs.y * inv;
            o.y = wv.y * (hv.y - sv.y * m) * rsqrtf(q - m * m * sv.y * (2.f - sv.y) + GN_EPS) + bv.y;
        }
        {
            float m = ms.z * inv, q = qs.z * inv;
            o.z = wv.z * (hv.z - sv.z * m) * rsqrtf(q - m * m * sv.z * (2.f - sv.z) + GN_EPS) + bv.z;
        }
        {
            float m = ms.w * inv, q = qs.w * inv;
            o.w = wv.w * (hv.w - sv.w * m) * rsqrtf(q - m * m * sv.w * (2.f - sv.w) + GN_EPS) + bv.w;
        }
        ((float4*)(out + (size_t)i * 256))[l] = o;
    }
}

extern "C" void kernel_launch(void* const* d_in, const int* in_sizes, int n_in,
                              void* d_out, int out_size, void* d_ws, size_t ws_size,
                              hipStream_t stream) {
    const float* x    = (const float*)d_in[0];
    const int*   ei   = (const int*)d_in[1];
    const int*   batch= (const int*)d_in[2];
    const float* Wl   = (const float*)d_in[3];
    const float* bl   = (const float*)d_in[4];
    const float* Wr   = (const float*)d_in[5];
    const float* br   = (const float*)d_in[6];
    const float* att  = (const float*)d_in[7];
    const float* bias = (const float*)d_in[8];
    const float* gnw  = (const float*)d_in[9];
    const float* gnb  = (const float*)d_in[10];
    const float* gms  = (const float*)d_in[11];
    float* out = (float*)d_out;

    char* p = (char*)d_ws;
    auto alloc = [&](size_t bytes) -> char* {
        char* r = p;
        p += (bytes + 255) & ~(size_t)255;
        return r;
    };
    unsigned short* Wt  = (unsigned short*)alloc((size_t)512 * 256 * 2);
    unsigned short* XL  = (unsigned short*)alloc((size_t)MPAD * 256 * 2);
    unsigned short* XRb = (unsigned short*)alloc((size_t)MPAD * 256 * 2);
    int* estart         = (int*)alloc((size_t)ECPAD * 4);
    int* ecursor        = (int*)alloc((size_t)ECPAD * 4);
    int* sedge          = (int*)alloc((size_t)(EPRIME + 192) * 4);
    // ---- contiguous zero-init region: ecount | ncount | gsum | gsq ----
    int* ecount         = (int*)alloc((size_t)ECPAD * 4);
    int* ncount         = (int*)alloc((size_t)NGRAPH * 4);
    float* gsum         = (float*)alloc((size_t)2 * NGRAPH * 256 * 4);  // gsum || gsq
    float* gsq          = gsum + NGRAPH * 256;
    size_t zbytes = (size_t)((char*)(gsum + 2 * NGRAPH * 256) - (char*)ecount);
    hipMemsetAsync(ecount, 0, zbytes, stream);

    k_pre<<<PREP_BLOCKS + HIST_BLOCKS, 256, 0, stream>>>(Wl, Wr, Wt, ei, batch,
                                                         ecount, ncount, sedge);
    k_gemm<<<MPAD / 64, 512, 0, stream>>>(x, Wt, bl, br, XL, XRb);

    k_scan_all<<<1, 1024, 0, stream>>>(ecount, estart, ecursor);
    k_scatter<<<HIST_BLOCKS, 256, 0, stream>>>(ei, ecursor, sedge);

    for (int s = 0; s < MSG_SPLIT; ++s)
        k_msg<<<MSG_RANGE / 4, 256, 0, stream>>>(XL, XRb, x, att, bias,
                                                 sedge, estart, ecount, out,
                                                 s * MSG_RANGE);

    k_gn_sum<<<(N_NODES + GN_ROWS - 1) / GN_ROWS, 256, 0, stream>>>(out, batch, gsum, gsq);
    k_final<<<FIN_BLOCKS, 256, 0, stream>>>(out, batch, gsum, gsq,
                                            ncount, gnw, gnb, gms);
}

// Round 8
// 352.319 us; speedup vs baseline: 1.1108x; 1.1108x over previous
//
#include <hip/hip_runtime.h>
#include <hip/hip_bf16.h>
#include <stdint.h>

#define N_NODES 50000
#define MPAD    50048          // 782 * 64
#define IN_DIM  256
#define EDGES   800000
#define EPRIME  (EDGES + N_NODES)
#define NGRAPH  64
#define GN_EPS  1e-5f
#define ECPAD   53248          // 208 * 256 = 13 * 4096, >= N_NODES
#define PREP_BLOCKS 512
#define HISTB   1661           // ceil(EPRIME/512)

typedef __attribute__((ext_vector_type(8))) short short8;
typedef __attribute__((ext_vector_type(4))) float floatx4;
typedef __attribute__((ext_vector_type(2))) float float2v;

__device__ __forceinline__ uint32_t pk2bf(float a, float b) {
    union { __hip_bfloat162 h; uint32_t u; } cv;
    cv.h = __float22bfloat162_rn(make_float2(a, b));
    return cv.u;
}

__device__ __forceinline__ unsigned short f2b(float f) {
    uint32_t u = __float_as_uint(f);
    u += 0x7fffu + ((u >> 16) & 1u);   // RTNE
    return (unsigned short)(u >> 16);
}

__device__ __forceinline__ float2v up2(uint32_t u) {
    float2v r;
    r[0] = __uint_as_float(u << 16);
    r[1] = __uint_as_float(u & 0xffff0000u);
    return r;
}

// ---------- fused: Wt2 build in MFMA-fragment order (blocks < 512)
//            + histograms, 2 edges/thread (blocks >= 512) ----------
// Wt2 layout: [g=ch>>4][kk=k>>5][lane=q*16+m][e=k&7], q=(k>>3)&3, m=ch&15
// -> a wave's B-fragment load for (g,kk) is base + lane*16B: fully coalesced.
__global__ __launch_bounds__(256) void k_pre(const float* __restrict__ Wl,
                                             const float* __restrict__ Wr,
                                             unsigned short* __restrict__ Wt,
                                             const int* __restrict__ ei,
                                             const int* __restrict__ batch,
                                             int* __restrict__ ecount,
                                             int* __restrict__ ncount,
                                             int* __restrict__ sedge) {
    if (blockIdx.x < PREP_BLOCKS) {
        int n = blockIdx.x;                 // one output channel per block
        int k = threadIdx.x;
        float v = (n < 256) ? Wl[k * 256 + n] : Wr[k * 256 + (n - 256)];
        int g = n >> 4, m = n & 15;
        int kk = k >> 5, q = (k >> 3) & 3, e = k & 7;
        Wt[(((g * 8 + kk) * 64) + q * 16 + m) * 8 + e] = f2b(v);
        return;
    }
    __shared__ int hist[NGRAPH];
    if (threadIdx.x < NGRAPH) hist[threadIdx.x] = 0;
    __syncthreads();
    int base = (blockIdx.x - PREP_BLOCKS) * 512 + threadIdx.x;
#pragma unroll
    for (int off = 0; off < 512; off += 256) {
        int e = base + off;
        if (e < EPRIME) {
            int d = (e < EDGES) ? ei[EDGES + e] : (e - EDGES);
            atomicAdd(&ecount[d], 1);
        }
        if (e < N_NODES) atomicAdd(&hist[batch[e]], 1);
    }
    if (blockIdx.x == PREP_BLOCKS && threadIdx.x < 192) sedge[EPRIME + threadIdx.x] = 0;
    __syncthreads();
    if (threadIdx.x < NGRAPH && hist[threadIdx.x])
        atomicAdd(&ncount[threadIdx.x], hist[threadIdx.x]);
}

// ---------- GEMM: [XL|XR] = bf16(x) @ [W_l|W_r], B from fragment-order Wt2 ----------
__global__ __launch_bounds__(512) void k_gemm(const float* __restrict__ x,
                                              const unsigned short* __restrict__ Wt,
                                              const float* __restrict__ bl,
                                              const float* __restrict__ br,
                                              unsigned short* __restrict__ XL,
                                              unsigned short* __restrict__ XR) {
    __shared__ unsigned short As[64 * 256];       // 32 KB
    int rbase = blockIdx.x * 64;
    int tid = threadIdx.x;

#pragma unroll
    for (int it = 0; it < 4; ++it) {
        int c = it * 512 + tid;
        int row = c >> 5, ch = c & 31;
        int gr = rbase + row;
        float4 f0, f1;
        if (gr < N_NODES) {
            const float4* src = (const float4*)(x + (size_t)gr * 256 + ch * 8);
            f0 = src[0]; f1 = src[1];
        } else {
            f0 = make_float4(0.f,0.f,0.f,0.f); f1 = f0;
        }
        uint32_t p0 = pk2bf(f0.x, f0.y), p1 = pk2bf(f0.z, f0.w);
        uint32_t p2 = pk2bf(f1.x, f1.y), p3 = pk2bf(f1.z, f1.w);
        uint4 hv = make_uint4(p0, p1, p2, p3);
        *(uint4*)(As + row * 256 + (ch ^ (row & 7)) * 8) = hv;
    }
    __syncthreads();

    int w = tid >> 6;
    int l = tid & 63;
    int m = l & 15, q = l >> 4;

    floatx4 acc[4][4];
#pragma unroll
    for (int rf = 0; rf < 4; ++rf)
#pragma unroll
        for (int cf = 0; cf < 4; ++cf)
            acc[rf][cf] = (floatx4){0.f, 0.f, 0.f, 0.f};

#pragma unroll
    for (int kk = 0; kk < 8; ++kk) {
        short8 a[4];
#pragma unroll
        for (int rf = 0; rf < 4; ++rf) {
            int row = rf * 16 + m;
            int ch = (kk * 4 + q) ^ (row & 7);
            a[rf] = *(const short8*)(As + row * 256 + ch * 8);
        }
#pragma unroll
        for (int cf = 0; cf < 4; ++cf) {
            // fragment-order Wt2: coalesced 1KB wave load (lane l -> +l*16B)
            short8 b = *(const short8*)(Wt + ((((w * 4 + cf) * 8 + kk) * 64) + l) * 8);
#pragma unroll
            for (int rf = 0; rf < 4; ++rf)   // A-slot = W frag -> D = C^T tile
                acc[rf][cf] = __builtin_amdgcn_mfma_f32_16x16x32_bf16(b, a[rf], acc[rf][cf], 0, 0, 0);
        }
    }

    // D layout (transposed compute): node = lane&15, channel = q*4 + reg.
    unsigned short* obase = (w < 4) ? XL : XR;
    const float* bptr = (w < 4) ? bl : br;
    int cb = (w & 3) * 64;
#pragma unroll
    for (int cf = 0; cf < 4; ++cf) {
        int chb = cb + cf * 16 + q * 4;
        float4 bv = *(const float4*)(bptr + chb);
#pragma unroll
        for (int rf = 0; rf < 4; ++rf) {
            int node = rbase + rf * 16 + m;
            uint2 o;
            o.x = pk2bf(acc[rf][cf][0] + bv.x, acc[rf][cf][1] + bv.y);
            o.y = pk2bf(acc[rf][cf][2] + bv.z, acc[rf][cf][3] + bv.w);
            *(uint2*)(obase + (size_t)node * 256 + chb) = o;  // pad rows exist
        }
    }
}

// ---------- single-workgroup device-wide exclusive scan of ecount ----------
__global__ __launch_bounds__(1024) void k_scan_all(const int* __restrict__ ecount,
                                                   int* __restrict__ estart,
                                                   int* __restrict__ ecursor) {
    __shared__ int wsum[16];
    int t = threadIdx.x, w = t >> 6, l = t & 63;
    int carry = 0;
    for (int base = 0; base < ECPAD; base += 4096) {
        int4 v = ((const int4*)(ecount + base))[t];
        int s = v.x + v.y + v.z + v.w;
        int sc = s;
#pragma unroll
        for (int off = 1; off < 64; off <<= 1) {
            int n = __shfl_up(sc, off);
            sc += (l >= off) ? n : 0;
        }
        if (l == 63) wsum[w] = sc;
        __syncthreads();
        int woff = 0, ctot = 0;
#pragma unroll
        for (int i = 0; i < 16; ++i) {
            int wi = wsum[i];
            woff += (i < w) ? wi : 0;
            ctot += wi;
        }
        int e0 = carry + woff + (sc - s);
        int4 o;
        o.x = e0; o.y = e0 + v.x; o.z = o.y + v.y; o.w = o.z + v.z;
        ((int4*)(estart  + base))[t] = o;
        ((int4*)(ecursor + base))[t] = o;
        carry += ctot;
        __syncthreads();   // protect wsum before next chunk overwrites
    }
}

// ---------- scatter edges into dst-sorted order, 2 edges/thread ----------
__global__ __launch_bounds__(256) void k_scatter(const int* __restrict__ ei,
                                                 int* __restrict__ ecursor,
                                                 int* __restrict__ sedge) {
    int base = blockIdx.x * 512 + threadIdx.x;
#pragma unroll
    for (int off = 0; off < 512; off += 256) {
        int e = base + off;
        if (e < EPRIME) {
            int s, d;
            if (e < EDGES) { s = ei[e]; d = ei[EDGES + e]; }
            else           { s = d = e - EDGES; }
            int pos = atomicAdd(&ecursor[d], 1);
            sedge[pos] = s;
        }
    }
}

// ---------- core: r4 body exactly (validated optimum), single launch ----------
__global__ __launch_bounds__(256) void k_msg(const unsigned short* __restrict__ XL,
                                             const unsigned short* __restrict__ XRb,
                                             const float* __restrict__ x,
                                             const float* __restrict__ att,
                                             const float* __restrict__ bias,
                                             const int* __restrict__ sedge,
                                             const int* __restrict__ estart,
                                             const int* __restrict__ ecount,
                                             float* __restrict__ out) {
    int d = (int)((blockIdx.x * 256 + threadIdx.x) >> 6);
    int l = threadIdx.x & 63;
    int lofs = l * 8;                 // byte offset of this lane's uint2 in a row

    float4 xin  = ((const float4*)(x + (size_t)d * 256))[l];
    float4 bvv  = ((const float4*)bias)[l];
    float4 attv = ((const float4*)att)[l];
    // leaky_relu(z,0.2) = 0.6z + 0.4|z|; fold coefficients into att
    float2v a601 = {0.6f * attv.x, 0.6f * attv.y};
    float2v a623 = {0.6f * attv.z, 0.6f * attv.w};
    float a40 = 0.4f * attv.x, a41 = 0.4f * attv.y;
    float a42 = 0.4f * attv.z, a43 = 0.4f * attv.w;

    uint2 xru = ((const uint2*)(XRb + (size_t)d * 256))[l];
    float2v xr01 = up2(xru.x), xr23 = up2(xru.y);

    int s0  = __builtin_amdgcn_readfirstlane(estart[d]);
    int cnt = __builtin_amdgcn_readfirstlane(ecount[d]);

    auto ldrow = [&](int src) -> uint2 {
        size_t off = ((size_t)(uint32_t)__builtin_amdgcn_readfirstlane(src)) << 9;
        return *(const uint2*)((const char*)XL + off + lofs);
    };

    float den0 = 0.f, den1 = 0.f, den2 = 0.f, den3 = 0.f;
    float2v A01 = {0.f,0.f}, A23 = {0.f,0.f};
    float2v B01 = {0.f,0.f}, B23 = {0.f,0.f};
    float2v C01 = {0.f,0.f}, C23 = {0.f,0.f};
    float2v D01 = {0.f,0.f}, D23 = {0.f,0.f};

    auto proc = [&](uint2 U, float& den, float2v& R01, float2v& R23) {
        float2v x01 = up2(U.x), x23 = up2(U.y);
        float2v z01 = x01 + xr01, z23 = x23 + xr23;
        float2v q = z01 * a601 + z23 * a623;      // 0.6 * att.z  (pk fma)
        float t0 = fmaf(fabsf(z01[0]), a40, q[0]);
        float t1 = fmaf(fabsf(z01[1]), a41, q[1]);
        t0 = fmaf(fabsf(z23[0]), a42, t0);
        t1 = fmaf(fabsf(z23[1]), a43, t1);
        float pp = t0 + t1;
        // 8-lane head reduce: xor1 (quad_perm), xor2 (quad_perm), xor4 (row_half_mirror)
        int pi = __float_as_int(pp);
        pp += __int_as_float(__builtin_amdgcn_update_dpp(0, pi, 0xB1, 0xF, 0xF, true));
        pi = __float_as_int(pp);
        pp += __int_as_float(__builtin_amdgcn_update_dpp(0, pi, 0x4E, 0xF, 0xF, true));
        pi = __float_as_int(pp);
        pp += __int_as_float(__builtin_amdgcn_update_dpp(0, pi, 0x141, 0xF, 0xF, true));
        float al = __expf(fminf(pp, 80.f));
        den += al;
        float2v al2 = {al, al};
        R01 += al2 * x01;
        R23 += al2 * x23;
    };

    // 4-deep prefetch: overshoot reads next dst's (valid) edges or zero pad
    uint2 P0 = ldrow(sedge[s0]);
    uint2 P1 = ldrow(sedge[s0 + 1]);
    uint2 P2 = ldrow(sedge[s0 + 2]);
    uint2 P3 = ldrow(sedge[s0 + 3]);

    int nq = cnt >> 2;
    for (int qq = 0; qq < nq; ++qq) {
        uint2 Q0 = P0, Q1 = P1, Q2 = P2, Q3 = P3;
        int nb = s0 + (qq + 1) * 4;
        P0 = ldrow(sedge[nb]);
        P1 = ldrow(sedge[nb + 1]);
        P2 = ldrow(sedge[nb + 2]);
        P3 = ldrow(sedge[nb + 3]);
        proc(Q0, den0, A01, A23);
        proc(Q1, den1, B01, B23);
        proc(Q2, den2, C01, C23);
        proc(Q3, den3, D01, D23);
    }
    int rem = cnt & 3;
    if (rem > 0) proc(P0, den0, A01, A23);
    if (rem > 1) proc(P1, den1, B01, B23);
    if (rem > 2) proc(P2, den2, C01, C23);

    float inv = 1.f / ((den0 + den1) + (den2 + den3) + 1e-16f);
    A01 = (A01 + B01) + (C01 + D01);
    A23 = (A23 + B23) + (C23 + D23);

    float h0 = A01[0] * inv + bvv.x + xin.x; h0 = (h0 > 0.f) ? h0 : (__expf(h0) - 1.f);
    float h1 = A01[1] * inv + bvv.y + xin.y; h1 = (h1 > 0.f) ? h1 : (__expf(h1) - 1.f);
    float h2 = A23[0] * inv + bvv.z + xin.z; h2 = (h2 > 0.f) ? h2 : (__expf(h2) - 1.f);
    float h3 = A23[1] * inv + bvv.w + xin.w; h3 = (h3 > 0.f) ? h3 : (__expf(h3) - 1.f);
    ((float4*)(out + (size_t)d * 256))[l] = make_float4(h0, h1, h2, h3);
}

// ---------- GraphNorm stats: float4 loads, 16 in flight, LDS reduce ----------
#define GN_ROWS 64
__global__ __launch_bounds__(256) void k_gn_sum(const float* __restrict__ h,
                                                const int* __restrict__ batch,
                                                float* __restrict__ gsum,
                                                float* __restrict__ gsq) {
    __shared__ int bsh[GN_ROWS];
    __shared__ float4 redS[4][64];
    __shared__ float4 redQ[4][64];
    int r0 = blockIdx.x * GN_ROWS;
    int t = threadIdx.x;
    if (t < GN_ROWS) {
        int i = r0 + t;
        bsh[t] = (i < N_NODES) ? batch[i] : -2;
    }
    __syncthreads();
    int l = t & 63, w = t >> 6;
    bool uni = (r0 + GN_ROWS <= N_NODES) && (bsh[0] == bsh[GN_ROWS - 1]);

    if (uni) {
        // fast path: whole block one graph; thread reads rows w, w+4, ..., w+60
        const float* hp = h + (size_t)(r0 + w) * 256 + l * 4;
        float4 s1 = make_float4(0.f, 0.f, 0.f, 0.f);
        float4 s2 = make_float4(0.f, 0.f, 0.f, 0.f);
#pragma unroll
        for (int k = 0; k < 16; ++k) {
            float4 v = *(const float4*)(hp + (size_t)k * 1024);
            s1.x += v.x; s1.y += v.y; s1.z += v.z; s1.w += v.w;
            s2.x = fmaf(v.x, v.x, s2.x);
            s2.y = fmaf(v.y, v.y, s2.y);
            s2.z = fmaf(v.z, v.z, s2.z);
            s2.w = fmaf(v.w, v.w, s2.w);
        }
        redS[w][l] = s1; redQ[w][l] = s2;
        __syncthreads();
        if (w == 0) {
            float4 b1 = redS[1][l], c1 = redS[2][l], d1 = redS[3][l];
            float4 b2 = redQ[1][l], c2 = redQ[2][l], d2 = redQ[3][l];
            s1.x += b1.x + c1.x + d1.x; s1.y += b1.y + c1.y + d1.y;
            s1.z += b1.z + c1.z + d1.z; s1.w += b1.w + c1.w + d1.w;
            s2.x += b2.x + c2.x + d2.x; s2.y += b2.y + c2.y + d2.y;
            s2.z += b2.z + c2.z + d2.z; s2.w += b2.w + c2.w + d2.w;
            int g = bsh[0];
            float* gp = gsum + g * 256 + l * 4;
            atomicAdd(gp + 0, s1.x); atomicAdd(gp + 1, s1.y);
            atomicAdd(gp + 2, s1.z); atomicAdd(gp + 3, s1.w);
            float* gq = gsq + g * 256 + l * 4;
            atomicAdd(gq + 0, s2.x); atomicAdd(gq + 1, s2.y);
            atomicAdd(gq + 2, s2.z); atomicAdd(gq + 3, s2.w);
        }
        return;
    }

    // slow path: boundary / tail block — per-row with flush-on-graph-change
    float4 s1 = make_float4(0.f, 0.f, 0.f, 0.f);
    float4 s2 = make_float4(0.f, 0.f, 0.f, 0.f);
    int g = (r0 + w < N_NODES) ? bsh[w] : -1;
    for (int j = w; j < GN_ROWS; j += 4) {
        int ii = r0 + j;
        if (ii >= N_NODES) break;
        int bg = bsh[j];
        if (bg != g) {
            float* gp = gsum + g * 256 + l * 4;
            atomicAdd(gp + 0, s1.x); atomicAdd(gp + 1, s1.y);
            atomicAdd(gp + 2, s1.z); atomicAdd(gp + 3, s1.w);
            float* gq = gsq + g * 256 + l * 4;
            atomicAdd(gq + 0, s2.x); atomicAdd(gq + 1, s2.y);
            atomicAdd(gq + 2, s2.z); atomicAdd(gq + 3, s2.w);
            s1 = make_float4(0.f, 0.f, 0.f, 0.f);
            s2 = make_float4(0.f, 0.f, 0.f, 0.f);
            g = bg;
        }
        float4 v = *(const float4*)(h + (size_t)ii * 256 + l * 4);
        s1.x += v.x; s1.y += v.y; s1.z += v.z; s1.w += v.w;
        s2.x = fmaf(v.x, v.x, s2.x);
        s2.y = fmaf(v.y, v.y, s2.y);
        s2.z = fmaf(v.z, v.z, s2.z);
        s2.w = fmaf(v.w, v.w, s2.w);
    }
    if (g >= 0) {
        float* gp = gsum + g * 256 + l * 4;
        atomicAdd(gp + 0, s1.x); atomicAdd(gp + 1, s1.y);
        atomicAdd(gp + 2, s1.z); atomicAdd(gp + 3, s1.w);
        float* gq = gsq + g * 256 + l * 4;
        atomicAdd(gq + 0, s2.x); atomicAdd(gq + 1, s2.y);
        atomicAdd(gq + 2, s2.z); atomicAdd(gq + 3, s2.w);
    }
}

// ---------- GraphNorm finalize: grid-stride, hoisted channel params ----------
#define FIN_BLOCKS 2048
__global__ __launch_bounds__(256) void k_final(float* __restrict__ out,
                                               const int* __restrict__ batch,
                                               const float* __restrict__ gsum,
                                               const float* __restrict__ gsq,
                                               const int* __restrict__ ncount,
                                               const float* __restrict__ gnw,
                                               const float* __restrict__ gnb,
                                               const float* __restrict__ gms) {
    int l = threadIdx.x & 63, wr = threadIdx.x >> 6;
    float4 wv = ((const float4*)gnw)[l];
    float4 bv = ((const float4*)gnb)[l];
    float4 sv = ((const float4*)gms)[l];
    for (int i = blockIdx.x * 4 + wr; i < N_NODES; i += FIN_BLOCKS * 4) {
        int g = batch[i];
        float inv = 1.f / fmaxf((float)ncount[g], 1.f);
        float4 hv = ((const float4*)(out + (size_t)i * 256))[l];
        float4 ms = ((const float4*)(gsum + g * 256))[l];
        float4 qs = ((const float4*)(gsq  + g * 256))[l];
        float4 o;
        {
            float m = ms.x * inv, q = qs.x * inv;
            o.x = wv.x * (hv.x - sv.x * m) * rsqrtf(q - m * m * sv.x * (2.f - sv.x) + GN_EPS) + bv.x;
        }
        {
            float m = ms.y * inv, q = qs.y * inv;
            o.y = wv.y * (hv.y - sv.y * m) * rsqrtf(q - m * m * sv.y * (2.f - sv.y) + GN_EPS) + bv.y;
        }
        {
            float m = ms.z * inv, q = qs.z * inv;
            o.z = wv.z * (hv.z - sv.z * m) * rsqrtf(q - m * m * sv.z * (2.f - sv.z) + GN_EPS) + bv.z;
        }
        {
            float m = ms.w * inv, q = qs.w * inv;
            o.w = wv.w * (hv.w - sv.w * m) * rsqrtf(q - m * m * sv.w * (2.f - sv.w) + GN_EPS) + bv.w;
        }
        ((float4*)(out + (size_t)i * 256))[l] = o;
    }
}

extern "C" void kernel_launch(void* const* d_in, const int* in_sizes, int n_in,
                              void* d_out, int out_size, void* d_ws, size_t ws_size,
                              hipStream_t stream) {
    const float* x    = (const float*)d_in[0];
    const int*   ei   = (const int*)d_in[1];
    const int*   batch= (const int*)d_in[2];
    const float* Wl   = (const float*)d_in[3];
    const float* bl   = (const float*)d_in[4];
    const float* Wr   = (const float*)d_in[5];
    const float* br   = (const float*)d_in[6];
    const float* att  = (const float*)d_in[7];
    const float* bias = (const float*)d_in[8];
    const float* gnw  = (const float*)d_in[9];
    const float* gnb  = (const float*)d_in[10];
    const float* gms  = (const float*)d_in[11];
    float* out = (float*)d_out;

    char* p = (char*)d_ws;
    auto alloc = [&](size_t bytes) -> char* {
        char* r = p;
        p += (bytes + 255) & ~(size_t)255;
        return r;
    };
    unsigned short* Wt  = (unsigned short*)alloc((size_t)512 * 256 * 2);
    unsigned short* XL  = (unsigned short*)alloc((size_t)MPAD * 256 * 2);
    unsigned short* XRb = (unsigned short*)alloc((size_t)MPAD * 256 * 2);
    int* estart         = (int*)alloc((size_t)ECPAD * 4);
    int* ecursor        = (int*)alloc((size_t)ECPAD * 4);
    int* sedge          = (int*)alloc((size_t)(EPRIME + 192) * 4);
    // ---- contiguous zero-init region: ecount | ncount | gsum | gsq ----
    int* ecount         = (int*)alloc((size_t)ECPAD * 4);
    int* ncount         = (int*)alloc((size_t)NGRAPH * 4);
    float* gsum         = (float*)alloc((size_t)2 * NGRAPH * 256 * 4);  // gsum || gsq
    float* gsq          = gsum + NGRAPH * 256;
    size_t zbytes = (size_t)((char*)(gsum + 2 * NGRAPH * 256) - (char*)ecount);
    hipMemsetAsync(ecount, 0, zbytes, stream);

    k_pre<<<PREP_BLOCKS + HISTB, 256, 0, stream>>>(Wl, Wr, Wt, ei, batch,
                                                   ecount, ncount, sedge);
    k_gemm<<<MPAD / 64, 512, 0, stream>>>(x, Wt, bl, br, XL, XRb);

    k_scan_all<<<1, 1024, 0, stream>>>(ecount, estart, ecursor);
    k_scatter<<<HISTB, 256, 0, stream>>>(ei, ecursor, sedge);

    k_msg<<<N_NODES / 4, 256, 0, stream>>>(XL, XRb, x, att, bias,
                                           sedge, estart, ecount, out);

    k_gn_sum<<<(N_NODES + GN_ROWS - 1) / GN_ROWS, 256, 0, stream>>>(out, batch, gsum, gsq);
    k_final<<<FIN_BLOCKS, 256, 0, stream>>>(out, batch, gsum, gsq,
                                            ncount, gnw, gnb, gms);
}

// Round 9
// 341.549 us; speedup vs baseline: 1.1458x; 1.0315x over previous
//
#include <hip/hip_runtime.h>
#include <hip/hip_bf16.h>
#include <stdint.h>

#define N_NODES 50000
#define MPAD    50048          // 782 * 64
#define IN_DIM  256
#define EDGES   800000
#define EPRIME  (EDGES + N_NODES)
#define NGRAPH  64
#define GN_EPS  1e-5f
#define ECPAD   53248          // 208 * 256 = 13 * 4096, >= N_NODES
#define PREP_BLOCKS 512
#define HISTB   1661           // ceil(EPRIME/512)
#define GEMM_BLOCKS (MPAD / 64)   // 782
#define SC_BLOCKS   831           // ceil(EPRIME/1024), 512 thr x 2 edges
#define MSG_SPLIT 2
#define MSG_RANGE (N_NODES / MSG_SPLIT)   // 25000

typedef __attribute__((ext_vector_type(8))) short short8;
typedef __attribute__((ext_vector_type(4))) float floatx4;
typedef __attribute__((ext_vector_type(2))) float float2v;

__device__ __forceinline__ uint32_t pk2bf(float a, float b) {
    union { __hip_bfloat162 h; uint32_t u; } cv;
    cv.h = __float22bfloat162_rn(make_float2(a, b));
    return cv.u;
}

__device__ __forceinline__ unsigned short f2b(float f) {
    uint32_t u = __float_as_uint(f);
    u += 0x7fffu + ((u >> 16) & 1u);   // RTNE
    return (unsigned short)(u >> 16);
}

__device__ __forceinline__ float2v up2(uint32_t u) {
    float2v r;
    r[0] = __uint_as_float(u << 16);
    r[1] = __uint_as_float(u & 0xffff0000u);
    return r;
}

// ---------- fused: Wt2 build in MFMA-fragment order (blocks < 512)
//            + histograms, 2 edges/thread (blocks >= 512) ----------
// Wt2 layout: [g=ch>>4][kk=k>>5][lane=q*16+m][e=k&7], q=(k>>3)&3, m=ch&15
__global__ __launch_bounds__(256) void k_pre(const float* __restrict__ Wl,
                                             const float* __restrict__ Wr,
                                             unsigned short* __restrict__ Wt,
                                             const int* __restrict__ ei,
                                             const int* __restrict__ batch,
                                             int* __restrict__ ecount,
                                             int* __restrict__ ncount,
                                             int* __restrict__ sedge) {
    if (blockIdx.x < PREP_BLOCKS) {
        int n = blockIdx.x;                 // one output channel per block
        int k = threadIdx.x;
        float v = (n < 256) ? Wl[k * 256 + n] : Wr[k * 256 + (n - 256)];
        int g = n >> 4, m = n & 15;
        int kk = k >> 5, q = (k >> 3) & 3, e = k & 7;
        Wt[(((g * 8 + kk) * 64) + q * 16 + m) * 8 + e] = f2b(v);
        return;
    }
    __shared__ int hist[NGRAPH];
    if (threadIdx.x < NGRAPH) hist[threadIdx.x] = 0;
    __syncthreads();
    int base = (blockIdx.x - PREP_BLOCKS) * 512 + threadIdx.x;
#pragma unroll
    for (int off = 0; off < 512; off += 256) {
        int e = base + off;
        if (e < EPRIME) {
            int d = (e < EDGES) ? ei[EDGES + e] : (e - EDGES);
            atomicAdd(&ecount[d], 1);
        }
        if (e < N_NODES) atomicAdd(&hist[batch[e]], 1);
    }
    if (blockIdx.x == PREP_BLOCKS && threadIdx.x < 192) sedge[EPRIME + threadIdx.x] = 0;
    __syncthreads();
    if (threadIdx.x < NGRAPH && hist[threadIdx.x])
        atomicAdd(&ncount[threadIdx.x], hist[threadIdx.x]);
}

// ---------- single-workgroup device-wide exclusive scan of ecount ----------
__global__ __launch_bounds__(1024) void k_scan_all(const int* __restrict__ ecount,
                                                   int* __restrict__ estart,
                                                   int* __restrict__ ecursor) {
    __shared__ int wsum[16];
    int t = threadIdx.x, w = t >> 6, l = t & 63;
    int carry = 0;
    for (int base = 0; base < ECPAD; base += 4096) {
        int4 v = ((const int4*)(ecount + base))[t];
        int s = v.x + v.y + v.z + v.w;
        int sc = s;
#pragma unroll
        for (int off = 1; off < 64; off <<= 1) {
            int n = __shfl_up(sc, off);
            sc += (l >= off) ? n : 0;
        }
        if (l == 63) wsum[w] = sc;
        __syncthreads();
        int woff = 0, ctot = 0;
#pragma unroll
        for (int i = 0; i < 16; ++i) {
            int wi = wsum[i];
            woff += (i < w) ? wi : 0;
            ctot += wi;
        }
        int e0 = carry + woff + (sc - s);
        int4 o;
        o.x = e0; o.y = e0 + v.x; o.z = o.y + v.y; o.w = o.z + v.z;
        ((int4*)(estart  + base))[t] = o;
        ((int4*)(ecursor + base))[t] = o;
        carry += ctot;
        __syncthreads();   // protect wsum before next chunk overwrites
    }
}

// ---------- fused GEMM + edge scatter: independent work, complementary pipes.
// Scatter blocks FIRST (longer, latency/atomic-bound); GEMM blocks follow
// (MFMA-bound). Co-resident waves interleave -> combined ~ max, not sum. ----------
__global__ __launch_bounds__(512) void k_gemm_sc(const float* __restrict__ x,
                                                 const unsigned short* __restrict__ Wt,
                                                 const float* __restrict__ bl,
                                                 const float* __restrict__ br,
                                                 unsigned short* __restrict__ XL,
                                                 unsigned short* __restrict__ XR,
                                                 const int* __restrict__ ei,
                                                 int* __restrict__ ecursor,
                                                 int* __restrict__ sedge) {
    __shared__ unsigned short As[64 * 256];       // 32 KB (gemm branch only)
    if (blockIdx.x < SC_BLOCKS) {
        int base = blockIdx.x * 1024 + threadIdx.x;
#pragma unroll
        for (int off = 0; off < 1024; off += 512) {
            int e = base + off;
            if (e < EPRIME) {
                int s, d;
                if (e < EDGES) { s = ei[e]; d = ei[EDGES + e]; }
                else           { s = d = e - EDGES; }
                int pos = atomicAdd(&ecursor[d], 1);
                sedge[pos] = s;
            }
        }
        return;
    }
    int rbase = (blockIdx.x - SC_BLOCKS) * 64;
    int tid = threadIdx.x;

#pragma unroll
    for (int it = 0; it < 4; ++it) {
        int c = it * 512 + tid;
        int row = c >> 5, ch = c & 31;
        int gr = rbase + row;
        float4 f0, f1;
        if (gr < N_NODES) {
            const float4* src = (const float4*)(x + (size_t)gr * 256 + ch * 8);
            f0 = src[0]; f1 = src[1];
        } else {
            f0 = make_float4(0.f,0.f,0.f,0.f); f1 = f0;
        }
        uint32_t p0 = pk2bf(f0.x, f0.y), p1 = pk2bf(f0.z, f0.w);
        uint32_t p2 = pk2bf(f1.x, f1.y), p3 = pk2bf(f1.z, f1.w);
        uint4 hv = make_uint4(p0, p1, p2, p3);
        *(uint4*)(As + row * 256 + (ch ^ (row & 7)) * 8) = hv;
    }
    __syncthreads();

    int w = tid >> 6;
    int l = tid & 63;
    int m = l & 15, q = l >> 4;

    floatx4 acc[4][4];
#pragma unroll
    for (int rf = 0; rf < 4; ++rf)
#pragma unroll
        for (int cf = 0; cf < 4; ++cf)
            acc[rf][cf] = (floatx4){0.f, 0.f, 0.f, 0.f};

#pragma unroll
    for (int kk = 0; kk < 8; ++kk) {
        short8 a[4];
#pragma unroll
        for (int rf = 0; rf < 4; ++rf) {
            int row = rf * 16 + m;
            int ch = (kk * 4 + q) ^ (row & 7);
            a[rf] = *(const short8*)(As + row * 256 + ch * 8);
        }
#pragma unroll
        for (int cf = 0; cf < 4; ++cf) {
            // fragment-order Wt2: coalesced 1KB wave load (lane l -> +l*16B)
            short8 b = *(const short8*)(Wt + ((((w * 4 + cf) * 8 + kk) * 64) + l) * 8);
#pragma unroll
            for (int rf = 0; rf < 4; ++rf)   // A-slot = W frag -> D = C^T tile
                acc[rf][cf] = __builtin_amdgcn_mfma_f32_16x16x32_bf16(b, a[rf], acc[rf][cf], 0, 0, 0);
        }
    }

    // D layout (transposed compute): node = lane&15, channel = q*4 + reg.
    unsigned short* obase = (w < 4) ? XL : XR;
    const float* bptr = (w < 4) ? bl : br;
    int cb = (w & 3) * 64;
#pragma unroll
    for (int cf = 0; cf < 4; ++cf) {
        int chb = cb + cf * 16 + q * 4;
        float4 bv = *(const float4*)(bptr + chb);
#pragma unroll
        for (int rf = 0; rf < 4; ++rf) {
            int node = rbase + rf * 16 + m;
            uint2 o;
            o.x = pk2bf(acc[rf][cf][0] + bv.x, acc[rf][cf][1] + bv.y);
            o.y = pk2bf(acc[rf][cf][2] + bv.z, acc[rf][cf][3] + bv.w);
            *(uint2*)(obase + (size_t)node * 256 + chb) = o;  // pad rows exist
        }
    }
}

// ---------- core: r4 body exactly (validated optimum), dst-range split x2 ----------
__global__ __launch_bounds__(256) void k_msg(const unsigned short* __restrict__ XL,
                                             const unsigned short* __restrict__ XRb,
                                             const float* __restrict__ x,
                                             const float* __restrict__ att,
                                             const float* __restrict__ bias,
                                             const int* __restrict__ sedge,
                                             const int* __restrict__ estart,
                                             const int* __restrict__ ecount,
                                             float* __restrict__ out,
                                             int lo) {
    int d = lo + (int)((blockIdx.x * 256 + threadIdx.x) >> 6);
    int l = threadIdx.x & 63;
    int lofs = l * 8;                 // byte offset of this lane's uint2 in a row

    float4 xin  = ((const float4*)(x + (size_t)d * 256))[l];
    float4 bvv  = ((const float4*)bias)[l];
    float4 attv = ((const float4*)att)[l];
    // leaky_relu(z,0.2) = 0.6z + 0.4|z|; fold coefficients into att
    float2v a601 = {0.6f * attv.x, 0.6f * attv.y};
    float2v a623 = {0.6f * attv.z, 0.6f * attv.w};
    float a40 = 0.4f * attv.x, a41 = 0.4f * attv.y;
    float a42 = 0.4f * attv.z, a43 = 0.4f * attv.w;

    uint2 xru = ((const uint2*)(XRb + (size_t)d * 256))[l];
    float2v xr01 = up2(xru.x), xr23 = up2(xru.y);

    int s0  = __builtin_amdgcn_readfirstlane(estart[d]);
    int cnt = __builtin_amdgcn_readfirstlane(ecount[d]);

    auto ldrow = [&](int src) -> uint2 {
        size_t off = ((size_t)(uint32_t)__builtin_amdgcn_readfirstlane(src)) << 9;
        return *(const uint2*)((const char*)XL + off + lofs);
    };

    float den0 = 0.f, den1 = 0.f, den2 = 0.f, den3 = 0.f;
    float2v A01 = {0.f,0.f}, A23 = {0.f,0.f};
    float2v B01 = {0.f,0.f}, B23 = {0.f,0.f};
    float2v C01 = {0.f,0.f}, C23 = {0.f,0.f};
    float2v D01 = {0.f,0.f}, D23 = {0.f,0.f};

    auto proc = [&](uint2 U, float& den, float2v& R01, float2v& R23) {
        float2v x01 = up2(U.x), x23 = up2(U.y);
        float2v z01 = x01 + xr01, z23 = x23 + xr23;
        float2v q = z01 * a601 + z23 * a623;      // 0.6 * att.z  (pk fma)
        float t0 = fmaf(fabsf(z01[0]), a40, q[0]);
        float t1 = fmaf(fabsf(z01[1]), a41, q[1]);
        t0 = fmaf(fabsf(z23[0]), a42, t0);
        t1 = fmaf(fabsf(z23[1]), a43, t1);
        float pp = t0 + t1;
        // 8-lane head reduce: xor1 (quad_perm), xor2 (quad_perm), xor4 (row_half_mirror)
        int pi = __float_as_int(pp);
        pp += __int_as_float(__builtin_amdgcn_update_dpp(0, pi, 0xB1, 0xF, 0xF, true));
        pi = __float_as_int(pp);
        pp += __int_as_float(__builtin_amdgcn_update_dpp(0, pi, 0x4E, 0xF, 0xF, true));
        pi = __float_as_int(pp);
        pp += __int_as_float(__builtin_amdgcn_update_dpp(0, pi, 0x141, 0xF, 0xF, true));
        float al = __expf(fminf(pp, 80.f));
        den += al;
        float2v al2 = {al, al};
        R01 += al2 * x01;
        R23 += al2 * x23;
    };

    // 4-deep prefetch: overshoot reads next dst's (valid) edges or zero pad
    uint2 P0 = ldrow(sedge[s0]);
    uint2 P1 = ldrow(sedge[s0 + 1]);
    uint2 P2 = ldrow(sedge[s0 + 2]);
    uint2 P3 = ldrow(sedge[s0 + 3]);

    int nq = cnt >> 2;
    for (int qq = 0; qq < nq; ++qq) {
        uint2 Q0 = P0, Q1 = P1, Q2 = P2, Q3 = P3;
        int nb = s0 + (qq + 1) * 4;
        P0 = ldrow(sedge[nb]);
        P1 = ldrow(sedge[nb + 1]);
        P2 = ldrow(sedge[nb + 2]);
        P3 = ldrow(sedge[nb + 3]);
        proc(Q0, den0, A01, A23);
        proc(Q1, den1, B01, B23);
        proc(Q2, den2, C01, C23);
        proc(Q3, den3, D01, D23);
    }
    int rem = cnt & 3;
    if (rem > 0) proc(P0, den0, A01, A23);
    if (rem > 1) proc(P1, den1, B01, B23);
    if (rem > 2) proc(P2, den2, C01, C23);

    float inv = 1.f / ((den0 + den1) + (den2 + den3) + 1e-16f);
    A01 = (A01 + B01) + (C01 + D01);
    A23 = (A23 + B23) + (C23 + D23);

    float h0 = A01[0] * inv + bvv.x + xin.x; h0 = (h0 > 0.f) ? h0 : (__expf(h0) - 1.f);
    float h1 = A01[1] * inv + bvv.y + xin.y; h1 = (h1 > 0.f) ? h1 : (__expf(h1) - 1.f);
    float h2 = A23[0] * inv + bvv.z + xin.z; h2 = (h2 > 0.f) ? h2 : (__expf(h2) - 1.f);
    float h3 = A23[1] * inv + bvv.w + xin.w; h3 = (h3 > 0.f) ? h3 : (__expf(h3) - 1.f);
    ((float4*)(out + (size_t)d * 256))[l] = make_float4(h0, h1, h2, h3);
}

// ---------- GraphNorm stats: float4 loads, 16 in flight, LDS reduce ----------
#define GN_ROWS 64
__global__ __launch_bounds__(256) void k_gn_sum(const float* __restrict__ h,
                                                const int* __restrict__ batch,
                                                float* __restrict__ gsum,
                                                float* __restrict__ gsq) {
    __shared__ int bsh[GN_ROWS];
    __shared__ float4 redS[4][64];
    __shared__ float4 redQ[4][64];
    int r0 = blockIdx.x * GN_ROWS;
    int t = threadIdx.x;
    if (t < GN_ROWS) {
        int i = r0 + t;
        bsh[t] = (i < N_NODES) ? batch[i] : -2;
    }
    __syncthreads();
    int l = t & 63, w = t >> 6;
    bool uni = (r0 + GN_ROWS <= N_NODES) && (bsh[0] == bsh[GN_ROWS - 1]);

    if (uni) {
        // fast path: whole block one graph; thread reads rows w, w+4, ..., w+60
        const float* hp = h + (size_t)(r0 + w) * 256 + l * 4;
        float4 s1 = make_float4(0.f, 0.f, 0.f, 0.f);
        float4 s2 = make_float4(0.f, 0.f, 0.f, 0.f);
#pragma unroll
        for (int k = 0; k < 16; ++k) {
            float4 v = *(const float4*)(hp + (size_t)k * 1024);
            s1.x += v.x; s1.y += v.y; s1.z += v.z; s1.w += v.w;
            s2.x = fmaf(v.x, v.x, s2.x);
            s2.y = fmaf(v.y, v.y, s2.y);
            s2.z = fmaf(v.z, v.z, s2.z);
            s2.w = fmaf(v.w, v.w, s2.w);
        }
        redS[w][l] = s1; redQ[w][l] = s2;
        __syncthreads();
        if (w == 0) {
            float4 b1 = redS[1][l], c1 = redS[2][l], d1 = redS[3][l];
            float4 b2 = redQ[1][l], c2 = redQ[2][l], d2 = redQ[3][l];
            s1.x += b1.x + c1.x + d1.x; s1.y += b1.y + c1.y + d1.y;
            s1.z += b1.z + c1.z + d1.z; s1.w += b1.w + c1.w + d1.w;
            s2.x += b2.x + c2.x + d2.x; s2.y += b2.y + c2.y + d2.y;
            s2.z += b2.z + c2.z + d2.z; s2.w += b2.w + c2.w + d2.w;
            int g = bsh[0];
            float* gp = gsum + g * 256 + l * 4;
            atomicAdd(gp + 0, s1.x); atomicAdd(gp + 1, s1.y);
            atomicAdd(gp + 2, s1.z); atomicAdd(gp + 3, s1.w);
            float* gq = gsq + g * 256 + l * 4;
            atomicAdd(gq + 0, s2.x); atomicAdd(gq + 1, s2.y);
            atomicAdd(gq + 2, s2.z); atomicAdd(gq + 3, s2.w);
        }
        return;
    }

    // slow path: boundary / tail block — per-row with flush-on-graph-change
    float4 s1 = make_float4(0.f, 0.f, 0.f, 0.f);
    float4 s2 = make_float4(0.f, 0.f, 0.f, 0.f);
    int g = (r0 + w < N_NODES) ? bsh[w] : -1;
    for (int j = w; j < GN_ROWS; j += 4) {
        int ii = r0 + j;
        if (ii >= N_NODES) break;
        int bg = bsh[j];
        if (bg != g) {
            float* gp = gsum + g * 256 + l * 4;
            atomicAdd(gp + 0, s1.x); atomicAdd(gp + 1, s1.y);
            atomicAdd(gp + 2, s1.z); atomicAdd(gp + 3, s1.w);
            float* gq = gsq + g * 256 + l * 4;
            atomicAdd(gq + 0, s2.x); atomicAdd(gq + 1, s2.y);
            atomicAdd(gq + 2, s2.z); atomicAdd(gq + 3, s2.w);
            s1 = make_float4(0.f, 0.f, 0.f, 0.f);
            s2 = make_float4(0.f, 0.f, 0.f, 0.f);
            g = bg;
        }
        float4 v = *(const float4*)(h + (size_t)ii * 256 + l * 4);
        s1.x += v.x; s1.y += v.y; s1.z += v.z; s1.w += v.w;
        s2.x = fmaf(v.x, v.x, s2.x);
        s2.y = fmaf(v.y, v.y, s2.y);
        s2.z = fmaf(v.z, v.z, s2.z);
        s2.w = fmaf(v.w, v.w, s2.w);
    }
    if (g >= 0) {
        float* gp = gsum + g * 256 + l * 4;
        atomicAdd(gp + 0, s1.x); atomicAdd(gp + 1, s1.y);
        atomicAdd(gp + 2, s1.z); atomicAdd(gp + 3, s1.w);
        float* gq = gsq + g * 256 + l * 4;
        atomicAdd(gq + 0, s2.x); atomicAdd(gq + 1, s2.y);
        atomicAdd(gq + 2, s2.z); atomicAdd(gq + 3, s2.w);
    }
}

// ---------- GraphNorm finalize: grid-stride, hoisted channel params ----------
#define FIN_BLOCKS 2048
__global__ __launch_bounds__(256) void k_final(float* __restrict__ out,
                                               const int* __restrict__ batch,
                                               const float* __restrict__ gsum,
                                               const float* __restrict__ gsq,
                                               const int* __restrict__ ncount,
                                               const float* __restrict__ gnw,
                                               const float* __restrict__ gnb,
                                               const float* __restrict__ gms) {
    int l = threadIdx.x & 63, wr = threadIdx.x >> 6;
    float4 wv = ((const float4*)gnw)[l];
    float4 bv = ((const float4*)gnb)[l];
    float4 sv = ((const float4*)gms)[l];
    for (int i = blockIdx.x * 4 + wr; i < N_NODES; i += FIN_BLOCKS * 4) {
        int g = batch[i];
        float inv = 1.f / fmaxf((float)ncount[g], 1.f);
        float4 hv = ((const float4*)(out + (size_t)i * 256))[l];
        float4 ms = ((const float4*)(gsum + g * 256))[l];
        float4 qs = ((const float4*)(gsq  + g * 256))[l];
        float4 o;
        {
            float m = ms.x * inv, q = qs.x * inv;
            o.x = wv.x * (hv.x - sv.x * m) * rsqrtf(q - m * m * sv.x * (2.f - sv.x) + GN_EPS) + bv.x;
        }
        {
            float m = ms.y * inv, q = qs.y * inv;
            o.y = wv.y * (hv.y - sv.y * m) * rsqrtf(q - m * m * sv.y * (2.f - sv.y) + GN_EPS) + bv.y;
        }
        {
            float m = ms.z * inv, q = qs.z * inv;
            o.z = wv.z * (hv.z - sv.z * m) * rsqrtf(q - m * m * sv.z * (2.f - sv.z) + GN_EPS) + bv.z;
        }
        {
            float m = ms.w * inv, q = qs.w * inv;
            o.w = wv.w * (hv.w - sv.w * m) * rsqrtf(q - m * m * sv.w * (2.f - sv.w) + GN_EPS) + bv.w;
        }
        ((float4*)(out + (size_t)i * 256))[l] = o;
    }
}

extern "C" void kernel_launch(void* const* d_in, const int* in_sizes, int n_in,
                              void* d_out, int out_size, void* d_ws, size_t ws_size,
                              hipStream_t stream) {
    const float* x    = (const float*)d_in[0];
    const int*   ei   = (const int*)d_in[1];
    const int*   batch= (const int*)d_in[2];
    const float* Wl   = (const float*)d_in[3];
    const float* bl   = (const float*)d_in[4];
    const float* Wr   = (const float*)d_in[5];
    const float* br   = (const float*)d_in[6];
    const float* att  = (const float*)d_in[7];
    const float* bias = (const float*)d_in[8];
    const float* gnw  = (const float*)d_in[9];
    const float* gnb  = (const float*)d_in[10];
    const float* gms  = (const float*)d_in[11];
    float* out = (float*)d_out;

    char* p = (char*)d_ws;
    auto alloc = [&](size_t bytes) -> char* {
        char* r = p;
        p += (bytes + 255) & ~(size_t)255;
        return r;
    };
    unsigned short* Wt  = (unsigned short*)alloc((size_t)512 * 256 * 2);
    unsigned short* XL  = (unsigned short*)alloc((size_t)MPAD * 256 * 2);
    unsigned short* XRb = (unsigned short*)alloc((size_t)MPAD * 256 * 2);
    int* estart         = (int*)alloc((size_t)ECPAD * 4);
    int* ecursor        = (int*)alloc((size_t)ECPAD * 4);
    int* sedge          = (int*)alloc((size_t)(EPRIME + 192) * 4);
    // ---- contiguous zero-init region: ecount | ncount | gsum | gsq ----
    int* ecount         = (int*)alloc((size_t)ECPAD * 4);
    int* ncount         = (int*)alloc((size_t)NGRAPH * 4);
    float* gsum         = (float*)alloc((size_t)2 * NGRAPH * 256 * 4);  // gsum || gsq
    float* gsq          = gsum + NGRAPH * 256;
    size_t zbytes = (size_t)((char*)(gsum + 2 * NGRAPH * 256) - (char*)ecount);
    hipMemsetAsync(ecount, 0, zbytes, stream);

    k_pre<<<PREP_BLOCKS + HISTB, 256, 0, stream>>>(Wl, Wr, Wt, ei, batch,
                                                   ecount, ncount, sedge);
    k_scan_all<<<1, 1024, 0, stream>>>(ecount, estart, ecursor);

    k_gemm_sc<<<SC_BLOCKS + GEMM_BLOCKS, 512, 0, stream>>>(x, Wt, bl, br, XL, XRb,
                                                           ei, ecursor, sedge);

    for (int s = 0; s < MSG_SPLIT; ++s)
        k_msg<<<MSG_RANGE / 4, 256, 0, stream>>>(XL, XRb, x, att, bias,
                                                 sedge, estart, ecount, out,
                                                 s * MSG_RANGE);

    k_gn_sum<<<(N_NODES + GN_ROWS - 1) / GN_ROWS, 256, 0, stream>>>(out, batch, gsum, gsq);
    k_final<<<FIN_BLOCKS, 256, 0, stream>>>(out, batch, gsum, gsq,
                                            ncount, gnw, gnb, gms);
}